// Round 1
// baseline (1707.941 us; speedup 1.0000x reference)
//
#include <hip/hip_runtime.h>
#include <hip/hip_bf16.h>
#include <cstddef>
#include <cstdint>

#define BB 4
#define NN 16
#define GG 64          // BB*NN
#define LL 2048
#define EE 32768
#define EF (EE + LL)   // edges + self loops
#define C0 64
#define C1 128
#define CC 256
#define EPS 1e-5f

// ---------------- edge preprocessing ----------------

__global__ void detect_kernel(const int* __restrict__ ei, int* __restrict__ flag) {
    int t = threadIdx.x;  // 64 threads, 1 wave
    int bad = 0;
    for (int i = t; i < 256; i += 64) bad |= (ei[2 * i + 1] != 0) ? 1 : 0;
    int any = __any(bad);
    if (t == 0) *flag = any ? 0 : 1;  // 1 => data is int64
}

__global__ void convert_kernel(const void* __restrict__ ei, const int* __restrict__ flag,
                               int* __restrict__ e32) {
    int i = blockIdx.x * 256 + threadIdx.x;
    if (i >= 2 * EE) return;
    int v;
    if (*flag)
        v = (int)((const long long*)ei)[i];
    else
        v = ((const int*)ei)[i];
    e32[i] = v;
}

__global__ void initdeg_kernel(float* __restrict__ deg, int* __restrict__ cnt) {
    int i = blockIdx.x * 256 + threadIdx.x;
    if (i < LL) { deg[i] = 2.0f; cnt[i] = 1; }   // self-loop weight 2, one slot
}

__global__ void deg_kernel(const int* __restrict__ e32, float* __restrict__ deg,
                           int* __restrict__ cnt) {
    int e = blockIdx.x * 256 + threadIdx.x;
    if (e >= EE) return;
    int d = e32[EE + e];
    atomicAdd(&deg[d], 1.0f);
    atomicAdd(&cnt[d], 1);
}

__global__ void dinv_kernel(const float* __restrict__ deg, float* __restrict__ dinv) {
    int i = blockIdx.x * 256 + threadIdx.x;
    if (i < LL) dinv[i] = rsqrtf(deg[i]);  // deg >= 2 always
}

__global__ void scan_kernel(const int* __restrict__ cnt, int* __restrict__ rowptr,
                            int* __restrict__ cursor) {
    __shared__ int part[256];
    int t = threadIdx.x;
    int base = t * 8;
    int loc[8];
    int s = 0;
#pragma unroll
    for (int j = 0; j < 8; ++j) { loc[j] = s; s += cnt[base + j]; }
    part[t] = s;
    __syncthreads();
    if (t == 0) {
        int run = 0;
        for (int i = 0; i < 256; ++i) { int v = part[i]; part[i] = run; run += v; }
    }
    __syncthreads();
    int off = part[t];
#pragma unroll
    for (int j = 0; j < 8; ++j) {
        int rp = off + loc[j];
        rowptr[base + j] = rp;
        cursor[base + j] = rp;
    }
    if (t == 255) rowptr[LL] = off + s;
}

__global__ void fill_kernel(const int* __restrict__ e32, const float* __restrict__ dinv,
                            int* __restrict__ cursor, int* __restrict__ cols,
                            float* __restrict__ vals) {
    int idx = blockIdx.x * 256 + threadIdx.x;
    if (idx >= EF) return;
    int s, d; float w;
    if (idx < EE) {
        s = e32[idx]; d = e32[EE + idx];
        w = dinv[s] * dinv[d];
    } else {
        int i = idx - EE;
        s = i; d = i;
        w = 2.0f * dinv[i] * dinv[i];
    }
    int pos = atomicAdd(&cursor[d], 1);
    cols[pos] = s;
    vals[pos] = w;
}

// ---------------- x transpose: [g][c=64][l] -> [g][l][64] ----------------

__global__ void transpose_x(const float* __restrict__ x, float* __restrict__ h) {
    __shared__ float t[32][33];
    int g = blockIdx.z, c0 = blockIdx.y * 32, l0 = blockIdx.x * 32;
    int tx = threadIdx.x, ty = threadIdx.y;  // 32 x 8
    const float* xp = x + ((size_t)g * C0 + c0) * LL + l0;
#pragma unroll
    for (int i = ty; i < 32; i += 8) t[i][tx] = xp[(size_t)i * LL + tx];  // t[c][l]
    __syncthreads();
    float* hp = h + ((size_t)g * LL + l0) * C0 + c0;
#pragma unroll
    for (int i = ty; i < 32; i += 8) hp[(size_t)i * C0 + tx] = t[tx][i];
}

// ---------------- GEMM: out[g][l][128] = h[g][l][K] @ W[K][128] ----------------
// grid (LL/64, GG), block 256. h stride == K (64 packed or 256).

template <int K>
__global__ __launch_bounds__(256) void gemm_f32(const float* __restrict__ h,
                                                const float* __restrict__ W,
                                                float* __restrict__ out) {
    const int g = blockIdx.y;
    const int l0 = blockIdx.x * 64;
    const float* hp = h + ((size_t)g * LL + l0) * K;
    float* op = out + ((size_t)g * LL + l0) * 128;
    __shared__ float hs[64 * 64];    // [row][k], KC=64
    __shared__ float ws[64 * 128];   // [k][f]
    const int tid = threadIdx.x;
    const int colq = (tid & 31);       // *4 -> col
    const int rowb = (tid >> 5) * 8;   // 8 rows per thread
    float acc[8][4];
#pragma unroll
    for (int r = 0; r < 8; ++r)
#pragma unroll
        for (int j = 0; j < 4; ++j) acc[r][j] = 0.0f;

    for (int k0 = 0; k0 < K; k0 += 64) {
        // stage h tile: 64 rows x 64 k = 1024 float4
#pragma unroll
        for (int it = 0; it < 4; ++it) {
            int f4 = tid + it * 256;
            int row = f4 >> 4, kq = f4 & 15;
            float4 v = *(const float4*)(hp + (size_t)row * K + k0 + kq * 4);
            *(float4*)(hs + row * 64 + kq * 4) = v;
        }
        // stage W tile: 64 k x 128 f = 2048 float4
#pragma unroll
        for (int it = 0; it < 8; ++it) {
            int f4 = tid + it * 256;
            int kk = f4 >> 5, c4 = f4 & 31;
            float4 v = *(const float4*)(W + (size_t)(k0 + kk) * 128 + c4 * 4);
            *(float4*)(ws + kk * 128 + c4 * 4) = v;
        }
        __syncthreads();
#pragma unroll 4
        for (int kc = 0; kc < 64; ++kc) {
            float4 wv = *(const float4*)(ws + kc * 128 + colq * 4);
#pragma unroll
            for (int r = 0; r < 8; ++r) {
                float hv = hs[(rowb + r) * 64 + kc];
                acc[r][0] = fmaf(hv, wv.x, acc[r][0]);
                acc[r][1] = fmaf(hv, wv.y, acc[r][1]);
                acc[r][2] = fmaf(hv, wv.z, acc[r][2]);
                acc[r][3] = fmaf(hv, wv.w, acc[r][3]);
            }
        }
        __syncthreads();
    }
#pragma unroll
    for (int r = 0; r < 8; ++r) {
        float4 v = make_float4(acc[r][0], acc[r][1], acc[r][2], acc[r][3]);
        *(float4*)(op + (size_t)(rowb + r) * 128 + colq * 4) = v;
    }
}

// ---------------- aggregation: a[g][l][f] = bias[f] + sum_e vals*hw[g][col][f] ----------------
// a stored with stride 256 (lower half of next h buffer). grid GG*LL/2, block 256.

__global__ void agg_kernel(const float* __restrict__ hw, const float* __restrict__ bias,
                           const int* __restrict__ rowptr, const int* __restrict__ cols,
                           const float* __restrict__ vals, float* __restrict__ aout) {
    int node = blockIdx.x * 2 + (threadIdx.x >> 7);  // g*LL + l
    int f = threadIdx.x & 127;
    int g = node >> 11, l = node & (LL - 1);
    const float* base = hw + (size_t)g * LL * 128;
    int j0 = rowptr[l], j1 = rowptr[l + 1];
    float acc = bias[f];
    for (int j = j0; j < j1; ++j) {
        acc = fmaf(vals[j], base[(size_t)cols[j] * 128 + f], acc);
    }
    aout[(size_t)node * CC + f] = acc;
}

// ---------------- max over n + BN stats ----------------
// a: stride-256 lower half. grid BB*(LL/16), block 128.

__global__ void maxstats_kernel(const float* __restrict__ a, float* __restrict__ amax,
                                float* __restrict__ sums, float* __restrict__ sumsq) {
    int bb = blockIdx.x >> 7;      // LL/16 = 128 tiles per b
    int lt = blockIdx.x & 127;
    int l0 = lt * 16;
    int f = threadIdx.x;
    float s = 0.f, ss = 0.f, sa = 0.f, ssa = 0.f;
    for (int li = 0; li < 16; ++li) {
        int l = l0 + li;
        float m = -3.402823466e38f;
#pragma unroll
        for (int n = 0; n < NN; ++n) {
            float v = a[(((size_t)(bb * NN + n) * LL + l) * CC) + f];
            m = fmaxf(m, v);
            s += v;
            ss = fmaf(v, v, ss);
        }
        amax[((size_t)bb * LL + l) * 128 + f] = m;
        sa += m;
        ssa = fmaf(m, m, ssa);
    }
    atomicAdd(&sums[f], s);
    atomicAdd(&sumsq[f], ss);
    atomicAdd(&sums[128 + f], sa);
    atomicAdd(&sumsq[128 + f], ssa);
}

__global__ void bnfinal_kernel(const float* __restrict__ sums, const float* __restrict__ sumsq,
                               const float* __restrict__ gamma, const float* __restrict__ beta,
                               float* __restrict__ sc) {
    int f = threadIdx.x;  // 256
    float cntv = (f < 128) ? (float)(BB * NN * LL) : (float)(BB * LL);
    float mean = sums[f] / cntv;
    float var = sumsq[f] / cntv - mean * mean;
    float s = gamma[f] * rsqrtf(var + EPS);
    sc[f] = s;
    sc[256 + f] = beta[f] - mean * s;
}

// ---------------- normalize + relu (in place over full 256 ch) ----------------
// grid GG*LL, block 256.

__global__ void norm_kernel(float* __restrict__ h, const float* __restrict__ amax,
                            const float* __restrict__ sc) {
    size_t node = blockIdx.x;  // g*LL + l
    int f = threadIdx.x;
    int g = (int)(node >> 11), l = (int)(node & (LL - 1));
    float v;
    if (f < 128)
        v = h[node * CC + f];
    else
        v = amax[((size_t)(g >> 4) * LL + l) * 128 + (f - 128)];
    float y = fmaxf(fmaf(v, sc[f], sc[256 + f]), 0.0f);
    h[node * CC + f] = y;
}

// ---------------- final transpose: [g][l][256] -> out[g][256][l] ----------------

__global__ void transpose_out(const float* __restrict__ h, float* __restrict__ out) {
    __shared__ float t[32][33];
    int g = blockIdx.z, f0 = blockIdx.y * 32, l0 = blockIdx.x * 32;
    int tx = threadIdx.x, ty = threadIdx.y;  // 32 x 8
    const float* hp = h + ((size_t)g * LL + l0) * CC + f0;
#pragma unroll
    for (int i = ty; i < 32; i += 8) t[i][tx] = hp[(size_t)i * CC + tx];  // t[l][f]
    __syncthreads();
    float* op = out + ((size_t)g * CC + f0) * LL + l0;
#pragma unroll
    for (int i = ty; i < 32; i += 8) op[(size_t)i * LL + tx] = t[tx][i];
}

// ---------------- launch ----------------

extern "C" void kernel_launch(void* const* d_in, const int* in_sizes, int n_in,
                              void* d_out, int out_size, void* d_ws, size_t ws_size,
                              hipStream_t stream) {
    const float* x = (const float*)d_in[0];
    const void* ei = d_in[1];
    const float* W[3] = {(const float*)d_in[2], (const float*)d_in[4], (const float*)d_in[6]};
    const float* bia[3] = {(const float*)d_in[3], (const float*)d_in[5], (const float*)d_in[7]};
    const float* gam[3] = {(const float*)d_in[8], (const float*)d_in[10], (const float*)d_in[12]};
    const float* bet[3] = {(const float*)d_in[9], (const float*)d_in[11], (const float*)d_in[13]};
    float* out = (float*)d_out;

    char* w = (char*)d_ws;
    float* hbuf0 = (float*)w;  w += (size_t)GG * LL * CC * 4;   // 134MB
    float* hbuf1 = (float*)w;  w += (size_t)GG * LL * CC * 4;   // 134MB
    float* hw    = (float*)w;  w += (size_t)GG * LL * 128 * 4;  // 67MB
    float* amax  = (float*)w;  w += (size_t)BB * LL * 128 * 4;  // 4MB
    int*   e32   = (int*)w;    w += (size_t)2 * EE * 4;
    float* deg   = (float*)w;  w += LL * 4;
    int*   cnt   = (int*)w;    w += LL * 4;
    int*   rowptr= (int*)w;    w += (LL + 4) * 4;
    int*   cursor= (int*)w;    w += LL * 4;
    int*   cols  = (int*)w;    w += EF * 4;
    float* vals  = (float*)w;  w += EF * 4;
    float* dinv  = (float*)w;  w += LL * 4;
    float* sums  = (float*)w;  w += 256 * 4;
    float* sumsq = (float*)w;  w += 256 * 4;
    float* sc    = (float*)w;  w += 512 * 4;
    int*   flag  = (int*)w;    w += 256;

    // edge preprocessing
    detect_kernel<<<1, 64, 0, stream>>>((const int*)ei, flag);
    convert_kernel<<<(2 * EE + 255) / 256, 256, 0, stream>>>(ei, flag, e32);
    initdeg_kernel<<<(LL + 255) / 256, 256, 0, stream>>>(deg, cnt);
    deg_kernel<<<(EE + 255) / 256, 256, 0, stream>>>(e32, deg, cnt);
    dinv_kernel<<<(LL + 255) / 256, 256, 0, stream>>>(deg, dinv);
    scan_kernel<<<1, 256, 0, stream>>>(cnt, rowptr, cursor);
    fill_kernel<<<(EF + 255) / 256, 256, 0, stream>>>(e32, dinv, cursor, cols, vals);

    // input transpose
    transpose_x<<<dim3(LL / 32, C0 / 32, GG), dim3(32, 8), 0, stream>>>(x, hbuf0);

    float* hcur = hbuf0;
    float* hnxt = hbuf1;
    for (int blk = 0; blk < 3; ++blk) {
        if (blk == 0)
            gemm_f32<64><<<dim3(LL / 64, GG), 256, 0, stream>>>(hcur, W[blk], hw);
        else
            gemm_f32<256><<<dim3(LL / 64, GG), 256, 0, stream>>>(hcur, W[blk], hw);

        agg_kernel<<<GG * LL / 2, 256, 0, stream>>>(hw, bia[blk], rowptr, cols, vals, hnxt);

        hipMemsetAsync(sums, 0, 2 * 256 * 4, stream);  // sums + sumsq adjacent
        maxstats_kernel<<<BB * (LL / 16), 128, 0, stream>>>(hnxt, amax, sums, sumsq);
        bnfinal_kernel<<<1, 256, 0, stream>>>(sums, sumsq, gam[blk], bet[blk], sc);
        norm_kernel<<<GG * LL, 256, 0, stream>>>(hnxt, amax, sc);

        float* t = hcur; hcur = hnxt; hnxt = t;
    }

    transpose_out<<<dim3(LL / 32, CC / 32, GG), dim3(32, 8), 0, stream>>>(hcur, out);
}

// Round 2
// 977.762 us; speedup vs baseline: 1.7468x; 1.7468x over previous
//
#include <hip/hip_runtime.h>
#include <hip/hip_bf16.h>
#include <cstddef>
#include <cstdint>

#define BB 4
#define NN 16
#define GG 64          // BB*NN
#define LL 2048
#define EE 32768
#define EF (EE + LL)   // edges + self loops
#define C0 64
#define C1 128
#define CC 256
#define EPS 1e-5f

struct __align__(8) Edge { int col; float val; };

// ---------------- edge preprocessing ----------------

__global__ void detect_kernel(const int* __restrict__ ei, int* __restrict__ flag) {
    int t = threadIdx.x;  // 64 threads, 1 wave
    int bad = 0;
    for (int i = t; i < 256; i += 64) bad |= (ei[2 * i + 1] != 0) ? 1 : 0;
    int any = __any(bad);
    if (t == 0) *flag = any ? 0 : 1;  // 1 => data is int64
}

__global__ void convert_kernel(const void* __restrict__ ei, const int* __restrict__ flag,
                               int* __restrict__ e32) {
    int i = blockIdx.x * 256 + threadIdx.x;
    if (i >= 2 * EE) return;
    int v;
    if (*flag)
        v = (int)((const long long*)ei)[i];
    else
        v = ((const int*)ei)[i];
    e32[i] = v;
}

__global__ void initdeg_kernel(float* __restrict__ deg, int* __restrict__ cnt) {
    int i = blockIdx.x * 256 + threadIdx.x;
    if (i < LL) { deg[i] = 2.0f; cnt[i] = 1; }   // self-loop weight 2, one slot
}

__global__ void deg_kernel(const int* __restrict__ e32, float* __restrict__ deg,
                           int* __restrict__ cnt) {
    int e = blockIdx.x * 256 + threadIdx.x;
    if (e >= EE) return;
    int d = e32[EE + e];
    atomicAdd(&deg[d], 1.0f);
    atomicAdd(&cnt[d], 1);
}

__global__ void dinv_kernel(const float* __restrict__ deg, float* __restrict__ dinv) {
    int i = blockIdx.x * 256 + threadIdx.x;
    if (i < LL) dinv[i] = rsqrtf(deg[i]);  // deg >= 2 always
}

__global__ void scan_kernel(const int* __restrict__ cnt, int* __restrict__ rowptr,
                            int* __restrict__ cursor) {
    __shared__ int part[256];
    int t = threadIdx.x;
    int base = t * 8;
    int loc[8];
    int s = 0;
#pragma unroll
    for (int j = 0; j < 8; ++j) { loc[j] = s; s += cnt[base + j]; }
    part[t] = s;
    __syncthreads();
    if (t == 0) {
        int run = 0;
        for (int i = 0; i < 256; ++i) { int v = part[i]; part[i] = run; run += v; }
    }
    __syncthreads();
    int off = part[t];
#pragma unroll
    for (int j = 0; j < 8; ++j) {
        int rp = off + loc[j];
        rowptr[base + j] = rp;
        cursor[base + j] = rp;
    }
    if (t == 255) rowptr[LL] = off + s;
}

__global__ void fill_kernel(const int* __restrict__ e32, const float* __restrict__ dinv,
                            int* __restrict__ cursor, Edge* __restrict__ edges) {
    int idx = blockIdx.x * 256 + threadIdx.x;
    if (idx >= EF) return;
    int s, d; float w;
    if (idx < EE) {
        s = e32[idx]; d = e32[EE + idx];
        w = dinv[s] * dinv[d];
    } else {
        int i = idx - EE;
        s = i; d = i;
        w = 2.0f * dinv[i] * dinv[i];
    }
    int pos = atomicAdd(&cursor[d], 1);
    edges[pos].col = s;
    edges[pos].val = w;
}

// ---------------- x transpose: [g][c=64][l] -> [g][l][64] ----------------

__global__ void transpose_x(const float* __restrict__ x, float* __restrict__ h) {
    __shared__ float t[32][33];
    int g = blockIdx.z, c0 = blockIdx.y * 32, l0 = blockIdx.x * 32;
    int tx = threadIdx.x, ty = threadIdx.y;  // 32 x 8
    const float* xp = x + ((size_t)g * C0 + c0) * LL + l0;
#pragma unroll
    for (int i = ty; i < 32; i += 8) t[i][tx] = xp[(size_t)i * LL + tx];  // t[c][l]
    __syncthreads();
    float* hp = h + ((size_t)g * LL + l0) * C0 + c0;
#pragma unroll
    for (int i = ty; i < 32; i += 8) hp[(size_t)i * C0 + tx] = t[tx][i];
}

// ---------------- GEMM: out[g][l][128] = h[g][l][K] @ W[K][128] ----------------
// grid (LL/64, GG), block 256. h stride == K (64 packed or 256).

template <int K>
__global__ __launch_bounds__(256) void gemm_f32(const float* __restrict__ h,
                                                const float* __restrict__ W,
                                                float* __restrict__ out) {
    const int g = blockIdx.y;
    const int l0 = blockIdx.x * 64;
    const float* hp = h + ((size_t)g * LL + l0) * K;
    float* op = out + ((size_t)g * LL + l0) * 128;
    __shared__ float hs[64 * 64];    // [row][k], KC=64
    __shared__ float ws[64 * 128];   // [k][f]
    const int tid = threadIdx.x;
    const int colq = (tid & 31);       // *4 -> col
    const int rowb = (tid >> 5) * 8;   // 8 rows per thread
    float acc[8][4];
#pragma unroll
    for (int r = 0; r < 8; ++r)
#pragma unroll
        for (int j = 0; j < 4; ++j) acc[r][j] = 0.0f;

    for (int k0 = 0; k0 < K; k0 += 64) {
        // stage h tile: 64 rows x 64 k = 1024 float4
#pragma unroll
        for (int it = 0; it < 4; ++it) {
            int f4 = tid + it * 256;
            int row = f4 >> 4, kq = f4 & 15;
            float4 v = *(const float4*)(hp + (size_t)row * K + k0 + kq * 4);
            *(float4*)(hs + row * 64 + kq * 4) = v;
        }
        // stage W tile: 64 k x 128 f = 2048 float4
#pragma unroll
        for (int it = 0; it < 8; ++it) {
            int f4 = tid + it * 256;
            int kk = f4 >> 5, c4 = f4 & 31;
            float4 v = *(const float4*)(W + (size_t)(k0 + kk) * 128 + c4 * 4);
            *(float4*)(ws + kk * 128 + c4 * 4) = v;
        }
        __syncthreads();
#pragma unroll 4
        for (int kc = 0; kc < 64; ++kc) {
            float4 wv = *(const float4*)(ws + kc * 128 + colq * 4);
#pragma unroll
            for (int r = 0; r < 8; ++r) {
                float hv = hs[(rowb + r) * 64 + kc];
                acc[r][0] = fmaf(hv, wv.x, acc[r][0]);
                acc[r][1] = fmaf(hv, wv.y, acc[r][1]);
                acc[r][2] = fmaf(hv, wv.z, acc[r][2]);
                acc[r][3] = fmaf(hv, wv.w, acc[r][3]);
            }
        }
        __syncthreads();
    }
#pragma unroll
    for (int r = 0; r < 8; ++r) {
        float4 v = make_float4(acc[r][0], acc[r][1], acc[r][2], acc[r][3]);
        *(float4*)(op + (size_t)(rowb + r) * 128 + colq * 4) = v;
    }
}

// ---------------- aggregation: a[g][l][f] = bias[f] + sum_e val*hw[g][col][f] ----------------
// One wave per node, lane handles channels {2*lane, 2*lane+1}. Edge list preloaded
// into lane registers (one 8B coalesced load), broadcast via shfl; gathers unrolled x4.
// a stored with stride 256 (lower half of next h buffer). grid GG*LL/4, block 256.

__global__ __launch_bounds__(256) void agg_kernel(const float* __restrict__ hw,
                                                  const float* __restrict__ bias,
                                                  const int* __restrict__ rowptr,
                                                  const Edge* __restrict__ edges,
                                                  float* __restrict__ aout) {
    const int lane = threadIdx.x & 63;
    int node = blockIdx.x * 4 + (threadIdx.x >> 6);  // g*LL + l
    node = __builtin_amdgcn_readfirstlane(node);
    const int g = node >> 11, l = node & (LL - 1);
    const float* __restrict__ base = hw + (size_t)g * LL * 128;
    const int j0 = rowptr[l];
    const int deg = rowptr[l + 1] - j0;

    float2 acc = *(const float2*)(bias + 2 * lane);

    for (int d0 = 0; d0 < deg; d0 += 64) {
        const int cnt = min(64, deg - d0);
        Edge e;
        e.col = 0; e.val = 0.0f;
        if (lane < cnt) e = edges[j0 + d0 + lane];
        int d = 0;
        for (; d + 4 <= cnt; d += 4) {
            int c0 = __shfl(e.col, d);
            int c1 = __shfl(e.col, d + 1);
            int c2 = __shfl(e.col, d + 2);
            int c3 = __shfl(e.col, d + 3);
            float w0 = __shfl(e.val, d);
            float w1 = __shfl(e.val, d + 1);
            float w2 = __shfl(e.val, d + 2);
            float w3 = __shfl(e.val, d + 3);
            float2 v0 = *(const float2*)(base + (size_t)c0 * 128 + 2 * lane);
            float2 v1 = *(const float2*)(base + (size_t)c1 * 128 + 2 * lane);
            float2 v2 = *(const float2*)(base + (size_t)c2 * 128 + 2 * lane);
            float2 v3 = *(const float2*)(base + (size_t)c3 * 128 + 2 * lane);
            acc.x = fmaf(w0, v0.x, acc.x); acc.y = fmaf(w0, v0.y, acc.y);
            acc.x = fmaf(w1, v1.x, acc.x); acc.y = fmaf(w1, v1.y, acc.y);
            acc.x = fmaf(w2, v2.x, acc.x); acc.y = fmaf(w2, v2.y, acc.y);
            acc.x = fmaf(w3, v3.x, acc.x); acc.y = fmaf(w3, v3.y, acc.y);
        }
        for (; d < cnt; ++d) {
            int c = __shfl(e.col, d);
            float wv = __shfl(e.val, d);
            float2 v = *(const float2*)(base + (size_t)c * 128 + 2 * lane);
            acc.x = fmaf(wv, v.x, acc.x);
            acc.y = fmaf(wv, v.y, acc.y);
        }
    }
    *(float2*)(aout + (size_t)node * CC + 2 * lane) = acc;
}

// ---------------- max over n + BN stats ----------------
// a: stride-256 lower half. grid BB*(LL/16), block 128.

__global__ void maxstats_kernel(const float* __restrict__ a, float* __restrict__ amax,
                                float* __restrict__ sums, float* __restrict__ sumsq) {
    int bb = blockIdx.x >> 7;      // LL/16 = 128 tiles per b
    int lt = blockIdx.x & 127;
    int l0 = lt * 16;
    int f = threadIdx.x;
    float s = 0.f, ss = 0.f, sa = 0.f, ssa = 0.f;
    for (int li = 0; li < 16; ++li) {
        int l = l0 + li;
        float m = -3.402823466e38f;
#pragma unroll
        for (int n = 0; n < NN; ++n) {
            float v = a[(((size_t)(bb * NN + n) * LL + l) * CC) + f];
            m = fmaxf(m, v);
            s += v;
            ss = fmaf(v, v, ss);
        }
        amax[((size_t)bb * LL + l) * 128 + f] = m;
        sa += m;
        ssa = fmaf(m, m, ssa);
    }
    atomicAdd(&sums[f], s);
    atomicAdd(&sumsq[f], ss);
    atomicAdd(&sums[128 + f], sa);
    atomicAdd(&sumsq[128 + f], ssa);
}

__global__ void bnfinal_kernel(const float* __restrict__ sums, const float* __restrict__ sumsq,
                               const float* __restrict__ gamma, const float* __restrict__ beta,
                               float* __restrict__ sc) {
    int f = threadIdx.x;  // 256
    float cntv = (f < 128) ? (float)(BB * NN * LL) : (float)(BB * LL);
    float mean = sums[f] / cntv;
    float var = sumsq[f] / cntv - mean * mean;
    float s = gamma[f] * rsqrtf(var + EPS);
    sc[f] = s;
    sc[256 + f] = beta[f] - mean * s;
}

// ---------------- normalize + relu (in place over full 256 ch) ----------------
// grid GG*LL, block 256.

__global__ void norm_kernel(float* __restrict__ h, const float* __restrict__ amax,
                            const float* __restrict__ sc) {
    size_t node = blockIdx.x;  // g*LL + l
    int f = threadIdx.x;
    int g = (int)(node >> 11), l = (int)(node & (LL - 1));
    float v;
    if (f < 128)
        v = h[node * CC + f];
    else
        v = amax[((size_t)(g >> 4) * LL + l) * 128 + (f - 128)];
    float y = fmaxf(fmaf(v, sc[f], sc[256 + f]), 0.0f);
    h[node * CC + f] = y;
}

// ---------------- final transpose: [g][l][256] -> out[g][256][l] ----------------

__global__ void transpose_out(const float* __restrict__ h, float* __restrict__ out) {
    __shared__ float t[32][33];
    int g = blockIdx.z, f0 = blockIdx.y * 32, l0 = blockIdx.x * 32;
    int tx = threadIdx.x, ty = threadIdx.y;  // 32 x 8
    const float* hp = h + ((size_t)g * LL + l0) * CC + f0;
#pragma unroll
    for (int i = ty; i < 32; i += 8) t[i][tx] = hp[(size_t)i * CC + tx];  // t[l][f]
    __syncthreads();
    float* op = out + ((size_t)g * CC + f0) * LL + l0;
#pragma unroll
    for (int i = ty; i < 32; i += 8) op[(size_t)i * LL + tx] = t[tx][i];
}

// ---------------- launch ----------------

extern "C" void kernel_launch(void* const* d_in, const int* in_sizes, int n_in,
                              void* d_out, int out_size, void* d_ws, size_t ws_size,
                              hipStream_t stream) {
    const float* x = (const float*)d_in[0];
    const void* ei = d_in[1];
    const float* W[3] = {(const float*)d_in[2], (const float*)d_in[4], (const float*)d_in[6]};
    const float* bia[3] = {(const float*)d_in[3], (const float*)d_in[5], (const float*)d_in[7]};
    const float* gam[3] = {(const float*)d_in[8], (const float*)d_in[10], (const float*)d_in[12]};
    const float* bet[3] = {(const float*)d_in[9], (const float*)d_in[11], (const float*)d_in[13]};
    float* out = (float*)d_out;

    char* w = (char*)d_ws;
    float* hbuf0 = (float*)w;  w += (size_t)GG * LL * CC * 4;   // 134MB
    float* hbuf1 = (float*)w;  w += (size_t)GG * LL * CC * 4;   // 134MB
    float* hw    = (float*)w;  w += (size_t)GG * LL * 128 * 4;  // 67MB
    float* amax  = (float*)w;  w += (size_t)BB * LL * 128 * 4;  // 4MB
    int*   e32   = (int*)w;    w += (size_t)2 * EE * 4;
    float* deg   = (float*)w;  w += LL * 4;
    int*   cnt   = (int*)w;    w += LL * 4;
    int*   rowptr= (int*)w;    w += (LL + 4) * 4;
    int*   cursor= (int*)w;    w += LL * 4;
    Edge*  edges = (Edge*)w;   w += (size_t)EF * 8;
    float* dinv  = (float*)w;  w += LL * 4;
    float* sums  = (float*)w;  w += 256 * 4;
    float* sumsq = (float*)w;  w += 256 * 4;
    float* sc    = (float*)w;  w += 512 * 4;
    int*   flag  = (int*)w;    w += 256;

    // edge preprocessing
    detect_kernel<<<1, 64, 0, stream>>>((const int*)ei, flag);
    convert_kernel<<<(2 * EE + 255) / 256, 256, 0, stream>>>(ei, flag, e32);
    initdeg_kernel<<<(LL + 255) / 256, 256, 0, stream>>>(deg, cnt);
    deg_kernel<<<(EE + 255) / 256, 256, 0, stream>>>(e32, deg, cnt);
    dinv_kernel<<<(LL + 255) / 256, 256, 0, stream>>>(deg, dinv);
    scan_kernel<<<1, 256, 0, stream>>>(cnt, rowptr, cursor);
    fill_kernel<<<(EF + 255) / 256, 256, 0, stream>>>(e32, dinv, cursor, edges);

    // input transpose
    transpose_x<<<dim3(LL / 32, C0 / 32, GG), dim3(32, 8), 0, stream>>>(x, hbuf0);

    float* hcur = hbuf0;
    float* hnxt = hbuf1;
    for (int blk = 0; blk < 3; ++blk) {
        if (blk == 0)
            gemm_f32<64><<<dim3(LL / 64, GG), 256, 0, stream>>>(hcur, W[blk], hw);
        else
            gemm_f32<256><<<dim3(LL / 64, GG), 256, 0, stream>>>(hcur, W[blk], hw);

        agg_kernel<<<GG * LL / 4, 256, 0, stream>>>(hw, bia[blk], rowptr, edges, hnxt);

        hipMemsetAsync(sums, 0, 2 * 256 * 4, stream);  // sums + sumsq adjacent
        maxstats_kernel<<<BB * (LL / 16), 128, 0, stream>>>(hnxt, amax, sums, sumsq);
        bnfinal_kernel<<<1, 256, 0, stream>>>(sums, sumsq, gam[blk], bet[blk], sc);
        norm_kernel<<<GG * LL, 256, 0, stream>>>(hnxt, amax, sc);

        float* t = hcur; hcur = hnxt; hnxt = t;
    }

    transpose_out<<<dim3(LL / 32, CC / 32, GG), dim3(32, 8), 0, stream>>>(hcur, out);
}

// Round 3
// 597.417 us; speedup vs baseline: 2.8589x; 1.6366x over previous
//
#include <hip/hip_runtime.h>
#include <hip/hip_bf16.h>
#include <cstddef>
#include <cstdint>

#define BB 4
#define NN 16
#define GG 64          // BB*NN
#define LL 2048
#define EE 32768
#define EF (EE + LL)   // edges + self loops
#define C0 64
#define CC 256
#define EPS 1e-5f

typedef __bf16 bf16x8 __attribute__((ext_vector_type(8)));
typedef __bf16 bf16x4 __attribute__((ext_vector_type(4)));
typedef __bf16 bf16x2 __attribute__((ext_vector_type(2)));
typedef float f32x4 __attribute__((ext_vector_type(4)));

struct __align__(8) Edge { int col; float val; };

// ---------------- edge preprocessing ----------------

__global__ void detect_kernel(const int* __restrict__ ei, int* __restrict__ flag) {
    int t = threadIdx.x;  // 64 threads, 1 wave
    int bad = 0;
    for (int i = t; i < 256; i += 64) bad |= (ei[2 * i + 1] != 0) ? 1 : 0;
    int any = __any(bad);
    if (t == 0) *flag = any ? 0 : 1;  // 1 => data is int64
}

__global__ void convert_kernel(const void* __restrict__ ei, const int* __restrict__ flag,
                               int* __restrict__ e32) {
    int i = blockIdx.x * 256 + threadIdx.x;
    if (i >= 2 * EE) return;
    int v;
    if (*flag)
        v = (int)((const long long*)ei)[i];
    else
        v = ((const int*)ei)[i];
    e32[i] = v;
}

__global__ void initdeg_kernel(float* __restrict__ deg, int* __restrict__ cnt) {
    int i = blockIdx.x * 256 + threadIdx.x;
    if (i < LL) { deg[i] = 2.0f; cnt[i] = 1; }   // self-loop weight 2, one slot
}

__global__ void deg_kernel(const int* __restrict__ e32, float* __restrict__ deg,
                           int* __restrict__ cnt) {
    int e = blockIdx.x * 256 + threadIdx.x;
    if (e >= EE) return;
    int d = e32[EE + e];
    atomicAdd(&deg[d], 1.0f);
    atomicAdd(&cnt[d], 1);
}

__global__ void dinv_kernel(const float* __restrict__ deg, float* __restrict__ dinv) {
    int i = blockIdx.x * 256 + threadIdx.x;
    if (i < LL) dinv[i] = rsqrtf(deg[i]);  // deg >= 2 always
}

__global__ void scan_kernel(const int* __restrict__ cnt, int* __restrict__ rowptr,
                            int* __restrict__ cursor) {
    __shared__ int part[256];
    int t = threadIdx.x;
    int base = t * 8;
    int loc[8];
    int s = 0;
#pragma unroll
    for (int j = 0; j < 8; ++j) { loc[j] = s; s += cnt[base + j]; }
    part[t] = s;
    __syncthreads();
    if (t == 0) {
        int run = 0;
        for (int i = 0; i < 256; ++i) { int v = part[i]; part[i] = run; run += v; }
    }
    __syncthreads();
    int off = part[t];
#pragma unroll
    for (int j = 0; j < 8; ++j) {
        int rp = off + loc[j];
        rowptr[base + j] = rp;
        cursor[base + j] = rp;
    }
    if (t == 255) rowptr[LL] = off + s;
}

__global__ void fill_kernel(const int* __restrict__ e32, const float* __restrict__ dinv,
                            int* __restrict__ cursor, Edge* __restrict__ edges) {
    int idx = blockIdx.x * 256 + threadIdx.x;
    if (idx >= EF) return;
    int s, d; float w;
    if (idx < EE) {
        s = e32[idx]; d = e32[EE + idx];
        w = dinv[s] * dinv[d];
    } else {
        int i = idx - EE;
        s = i; d = i;
        w = 2.0f * dinv[i] * dinv[i];
    }
    int pos = atomicAdd(&cursor[d], 1);
    edges[pos].col = s;
    edges[pos].val = w;
}

// ---------------- W pre-pack: W[K][128] f32 -> fragment-ordered bf16 ----------------
// Wf[((ks*8 + n16)*64 + lane)*8 + j] = bf16( W[ks*32 + (lane>>4)*8 + j][n16*16 + (lane&15)] )

__global__ void prep_w(const float* __restrict__ W, __bf16* __restrict__ Wf, int K) {
    int t = blockIdx.x * 256 + threadIdx.x;
    int total = (K / 32) * 8 * 64;
    if (t >= total) return;
    int lane = t & 63;
    int rest = t >> 6;
    int n16 = rest & 7;
    int ks = rest >> 3;
    int col = n16 * 16 + (lane & 15);
    int k0 = ks * 32 + (lane >> 4) * 8;
    bf16x8 v;
#pragma unroll
    for (int j = 0; j < 8; ++j) v[j] = (__bf16)W[(size_t)(k0 + j) * 128 + col];
    *(bf16x8*)(Wf + (size_t)t * 8) = v;
}

// ---------------- x transpose: [g][c=64][l] -> [g][l][64] f32 ----------------

__global__ void transpose_x(const float* __restrict__ x, float* __restrict__ h) {
    __shared__ float t[32][33];
    int g = blockIdx.z, c0 = blockIdx.y * 32, l0 = blockIdx.x * 32;
    int tx = threadIdx.x, ty = threadIdx.y;  // 32 x 8
    const float* xp = x + ((size_t)g * C0 + c0) * LL + l0;
#pragma unroll
    for (int i = ty; i < 32; i += 8) t[i][tx] = xp[(size_t)i * LL + tx];  // t[c][l]
    __syncthreads();
    float* hp = h + ((size_t)g * LL + l0) * C0 + c0;
#pragma unroll
    for (int i = ty; i < 32; i += 8) hp[(size_t)i * C0 + tx] = t[tx][i];
}

// ---------------- MFMA GEMM: hw[g][l][128] = act(A)[g][l][0:K] @ W[K][128] ----------------
// BN=true: A = relu(bn(concat(a, amax_broadcast))) applied on the fly at staging.
// grid (LL/64, GG), 256 threads (4 waves). Wave w computes rows [w*16, w*16+16) x all 128 cols.

template <int K, bool BN>
__global__ __launch_bounds__(256) void gemm_mfma(const float* __restrict__ A0,
                                                 const float* __restrict__ amax,
                                                 const float* __restrict__ scb,
                                                 const __bf16* __restrict__ Wf,
                                                 __bf16* __restrict__ hw) {
    const int g = blockIdx.y;
    const int l0 = blockIdx.x * 64;
    const int tid = threadIdx.x;
    const int wid = tid >> 6;
    const int lane = tid & 63;
    __shared__ __align__(16) __bf16 As[64 * 64];

    f32x4 acc[8];
#pragma unroll
    for (int nf = 0; nf < 8; ++nf) acc[nf] = (f32x4){0.f, 0.f, 0.f, 0.f};

    const int AS = BN ? 128 : 64;  // row stride of A0

    for (int kt = 0; kt < K / 64; ++kt) {
        // ---- stage A tile [64 rows][64 k] -> bf16 LDS, XOR-swizzled ----
#pragma unroll
        for (int it = 0; it < 4; ++it) {
            int f4 = tid + it * 256;     // 0..1023
            int row = f4 >> 4;           // 0..63
            int kq = (f4 & 15) * 4;      // 0..60
            int gk = kt * 64 + kq;
            float4 v;
            if constexpr (BN) {
                if (gk < 128)
                    v = *(const float4*)(A0 + ((size_t)g * LL + l0 + row) * 128 + gk);
                else
                    v = *(const float4*)(amax + ((size_t)(g >> 4) * LL + l0 + row) * 128 + (gk - 128));
                float4 s = *(const float4*)(scb + gk);
                float4 b = *(const float4*)(scb + 256 + gk);
                v.x = fmaxf(fmaf(v.x, s.x, b.x), 0.f);
                v.y = fmaxf(fmaf(v.y, s.y, b.y), 0.f);
                v.z = fmaxf(fmaf(v.z, s.z, b.z), 0.f);
                v.w = fmaxf(fmaf(v.w, s.w, b.w), 0.f);
            } else {
                v = *(const float4*)(A0 + ((size_t)g * LL + l0 + row) * 64 + gk);
            }
            int sidx = row * 64 + (kq ^ ((row & 7) << 3));
            bf16x4 pv = {(__bf16)v.x, (__bf16)v.y, (__bf16)v.z, (__bf16)v.w};
            *(bf16x4*)(&As[sidx]) = pv;
        }
        __syncthreads();
        // ---- MFMA over the 2 k-steps of this tile ----
#pragma unroll
        for (int ks2 = 0; ks2 < 2; ++ks2) {
            const int row = wid * 16 + (lane & 15);
            const int kk = ks2 * 32 + (lane >> 4) * 8;
            bf16x8 af = *(const bf16x8*)(&As[row * 64 + (kk ^ ((row & 7) << 3))]);
            const int ksg = kt * 2 + ks2;
            const __bf16* wp = Wf + (size_t)ksg * 8 * 512 + lane * 8;
#pragma unroll
            for (int nf = 0; nf < 8; ++nf) {
                bf16x8 bfr = *(const bf16x8*)(wp + nf * 512);
                acc[nf] = __builtin_amdgcn_mfma_f32_16x16x32_bf16(af, bfr, acc[nf], 0, 0, 0);
            }
        }
        __syncthreads();
    }
    // ---- epilogue: D frag col=lane&15, row=(lane>>4)*4+j ----
    __bf16* op = hw + ((size_t)g * LL + l0) * 128;
#pragma unroll
    for (int nf = 0; nf < 8; ++nf) {
        int col = nf * 16 + (lane & 15);
#pragma unroll
        for (int j = 0; j < 4; ++j) {
            int row = wid * 16 + (lane >> 4) * 4 + j;
            op[(size_t)row * 128 + col] = (__bf16)acc[nf][j];
        }
    }
}

// ---------------- aggregation: a[g][l][f] = bias[f] + sum_e val*hw[g][col][f] ----------------
// One wave per node; lane owns channels {2*lane, 2*lane+1}; edges preloaded to lane regs,
// broadcast via shfl; gathers (bf16x2) unrolled x4. grid GG*LL/4, block 256.

__global__ __launch_bounds__(256) void agg_kernel(const __bf16* __restrict__ hw,
                                                  const float* __restrict__ bias,
                                                  const int* __restrict__ rowptr,
                                                  const Edge* __restrict__ edges,
                                                  float* __restrict__ aout) {
    const int lane = threadIdx.x & 63;
    int node = blockIdx.x * 4 + (threadIdx.x >> 6);  // g*LL + l
    node = __builtin_amdgcn_readfirstlane(node);
    const int g = node >> 11, l = node & (LL - 1);
    const __bf16* __restrict__ base = hw + (size_t)g * LL * 128;
    const int j0 = rowptr[l];
    const int deg = rowptr[l + 1] - j0;

    float2 acc = *(const float2*)(bias + 2 * lane);

    for (int d0 = 0; d0 < deg; d0 += 64) {
        const int cnt = min(64, deg - d0);
        Edge e;
        e.col = 0; e.val = 0.0f;
        if (lane < cnt) e = edges[j0 + d0 + lane];
        int d = 0;
        for (; d + 4 <= cnt; d += 4) {
            int c0 = __shfl(e.col, d);
            int c1 = __shfl(e.col, d + 1);
            int c2 = __shfl(e.col, d + 2);
            int c3 = __shfl(e.col, d + 3);
            float w0 = __shfl(e.val, d);
            float w1 = __shfl(e.val, d + 1);
            float w2 = __shfl(e.val, d + 2);
            float w3 = __shfl(e.val, d + 3);
            bf16x2 v0 = *(const bf16x2*)(base + (size_t)c0 * 128 + 2 * lane);
            bf16x2 v1 = *(const bf16x2*)(base + (size_t)c1 * 128 + 2 * lane);
            bf16x2 v2 = *(const bf16x2*)(base + (size_t)c2 * 128 + 2 * lane);
            bf16x2 v3 = *(const bf16x2*)(base + (size_t)c3 * 128 + 2 * lane);
            acc.x = fmaf(w0, (float)v0[0], acc.x); acc.y = fmaf(w0, (float)v0[1], acc.y);
            acc.x = fmaf(w1, (float)v1[0], acc.x); acc.y = fmaf(w1, (float)v1[1], acc.y);
            acc.x = fmaf(w2, (float)v2[0], acc.x); acc.y = fmaf(w2, (float)v2[1], acc.y);
            acc.x = fmaf(w3, (float)v3[0], acc.x); acc.y = fmaf(w3, (float)v3[1], acc.y);
        }
        for (; d < cnt; ++d) {
            int c = __shfl(e.col, d);
            float wv = __shfl(e.val, d);
            bf16x2 v = *(const bf16x2*)(base + (size_t)c * 128 + 2 * lane);
            acc.x = fmaf(wv, (float)v[0], acc.x);
            acc.y = fmaf(wv, (float)v[1], acc.y);
        }
    }
    *(float2*)(aout + (size_t)node * 128 + 2 * lane) = acc;
}

// ---------------- max over n + BN stats ----------------
// a: [g][l][128] f32. grid BB*(LL/16), block 128.

__global__ void maxstats_kernel(const float* __restrict__ a, float* __restrict__ amax,
                                float* __restrict__ sums, float* __restrict__ sumsq) {
    int bb = blockIdx.x >> 7;      // LL/16 = 128 tiles per b
    int lt = blockIdx.x & 127;
    int l0 = lt * 16;
    int f = threadIdx.x;
    float s = 0.f, ss = 0.f, sa = 0.f, ssa = 0.f;
    for (int li = 0; li < 16; ++li) {
        int l = l0 + li;
        float m = -3.402823466e38f;
#pragma unroll
        for (int n = 0; n < NN; ++n) {
            float v = a[(((size_t)(bb * NN + n) * LL + l) * 128) + f];
            m = fmaxf(m, v);
            s += v;
            ss = fmaf(v, v, ss);
        }
        amax[((size_t)bb * LL + l) * 128 + f] = m;
        sa += m;
        ssa = fmaf(m, m, ssa);
    }
    atomicAdd(&sums[f], s);
    atomicAdd(&sumsq[f], ss);
    atomicAdd(&sums[128 + f], sa);
    atomicAdd(&sumsq[128 + f], ssa);
}

__global__ void bnfinal_kernel(const float* __restrict__ sums, const float* __restrict__ sumsq,
                               const float* __restrict__ gamma, const float* __restrict__ beta,
                               float* __restrict__ scb) {
    int f = threadIdx.x;  // 256
    float cntv = (f < 128) ? (float)(BB * NN * LL) : (float)(BB * LL);
    float mean = sums[f] / cntv;
    float var = sumsq[f] / cntv - mean * mean;
    float s = gamma[f] * rsqrtf(var + EPS);
    scb[f] = s;
    scb[256 + f] = beta[f] - mean * s;
}

// ---------------- final: out[g][f][l] = relu(bn(concat(a, amax))) transposed ----------------
// grid (LL/32, 8, GG), block (32,8).

__global__ void transpose_norm_out(const float* __restrict__ a, const float* __restrict__ amax,
                                   const float* __restrict__ scb, float* __restrict__ out) {
    __shared__ float t[32][33];
    int g = blockIdx.z, f0 = blockIdx.y * 32, l0 = blockIdx.x * 32;
    int tx = threadIdx.x, ty = threadIdx.y;  // 32 x 8
    int f = f0 + tx;
    float s = scb[f], b = scb[256 + f];
#pragma unroll
    for (int i = ty; i < 32; i += 8) {
        int l = l0 + i;
        float v;
        if (f0 < 128)
            v = a[((size_t)g * LL + l) * 128 + f];
        else
            v = amax[((size_t)(g >> 4) * LL + l) * 128 + (f - 128)];
        t[i][tx] = fmaxf(fmaf(v, s, b), 0.f);
    }
    __syncthreads();
    float* op = out + ((size_t)g * CC + f0) * LL + l0;
#pragma unroll
    for (int i = ty; i < 32; i += 8) op[(size_t)i * LL + tx] = t[tx][i];
}

// ---------------- launch ----------------

extern "C" void kernel_launch(void* const* d_in, const int* in_sizes, int n_in,
                              void* d_out, int out_size, void* d_ws, size_t ws_size,
                              hipStream_t stream) {
    const float* x = (const float*)d_in[0];
    const void* ei = d_in[1];
    const float* W[3] = {(const float*)d_in[2], (const float*)d_in[4], (const float*)d_in[6]};
    const float* bia[3] = {(const float*)d_in[3], (const float*)d_in[5], (const float*)d_in[7]};
    const float* gam[3] = {(const float*)d_in[8], (const float*)d_in[10], (const float*)d_in[12]};
    const float* bet[3] = {(const float*)d_in[9], (const float*)d_in[11], (const float*)d_in[13]};
    float* out = (float*)d_out;

    char* w = (char*)d_ws;
    float* h0   = (float*)w;  w += (size_t)GG * LL * C0 * 4;    // 33.5MB
    float* a    = (float*)w;  w += (size_t)GG * LL * 128 * 4;   // 67MB
    __bf16* hw  = (__bf16*)w; w += (size_t)GG * LL * 128 * 2;   // 33.5MB
    float* amax = (float*)w;  w += (size_t)BB * LL * 128 * 4;   // 4MB
    __bf16* Wf[3];
    Wf[0] = (__bf16*)w; w += 65536 * 2;
    Wf[1] = (__bf16*)w; w += 65536 * 2;
    Wf[2] = (__bf16*)w; w += 65536 * 2;
    int*   e32   = (int*)w;    w += (size_t)2 * EE * 4;
    float* deg   = (float*)w;  w += LL * 4;
    int*   cnt   = (int*)w;    w += LL * 4;
    int*   rowptr= (int*)w;    w += (LL + 4) * 4;
    int*   cursor= (int*)w;    w += LL * 4;
    Edge*  edges = (Edge*)w;   w += (size_t)EF * 8;
    float* dinv  = (float*)w;  w += LL * 4;
    float* sums  = (float*)w;  w += 256 * 4;
    float* sumsq = (float*)w;  w += 256 * 4;
    float* scb   = (float*)w;  w += 512 * 4;
    int*   flag  = (int*)w;    w += 256;

    // edge preprocessing
    detect_kernel<<<1, 64, 0, stream>>>((const int*)ei, flag);
    convert_kernel<<<(2 * EE + 255) / 256, 256, 0, stream>>>(ei, flag, e32);
    initdeg_kernel<<<(LL + 255) / 256, 256, 0, stream>>>(deg, cnt);
    deg_kernel<<<(EE + 255) / 256, 256, 0, stream>>>(e32, deg, cnt);
    dinv_kernel<<<(LL + 255) / 256, 256, 0, stream>>>(deg, dinv);
    scan_kernel<<<1, 256, 0, stream>>>(cnt, rowptr, cursor);
    fill_kernel<<<(EF + 255) / 256, 256, 0, stream>>>(e32, dinv, cursor, edges);

    // weight pre-pack
    prep_w<<<(1024 + 255) / 256, 256, 0, stream>>>(W[0], Wf[0], 64);
    prep_w<<<(4096 + 255) / 256, 256, 0, stream>>>(W[1], Wf[1], 256);
    prep_w<<<(4096 + 255) / 256, 256, 0, stream>>>(W[2], Wf[2], 256);

    // input transpose
    transpose_x<<<dim3(LL / 32, C0 / 32, GG), dim3(32, 8), 0, stream>>>(x, h0);

    // block 1
    gemm_mfma<64, false><<<dim3(LL / 64, GG), 256, 0, stream>>>(h0, amax, scb, Wf[0], hw);
    agg_kernel<<<GG * LL / 4, 256, 0, stream>>>(hw, bia[0], rowptr, edges, a);
    hipMemsetAsync(sums, 0, 2 * 256 * 4, stream);
    maxstats_kernel<<<BB * (LL / 16), 128, 0, stream>>>(a, amax, sums, sumsq);
    bnfinal_kernel<<<1, 256, 0, stream>>>(sums, sumsq, gam[0], bet[0], scb);

    // block 2
    gemm_mfma<256, true><<<dim3(LL / 64, GG), 256, 0, stream>>>(a, amax, scb, Wf[1], hw);
    agg_kernel<<<GG * LL / 4, 256, 0, stream>>>(hw, bia[1], rowptr, edges, a);
    hipMemsetAsync(sums, 0, 2 * 256 * 4, stream);
    maxstats_kernel<<<BB * (LL / 16), 128, 0, stream>>>(a, amax, sums, sumsq);
    bnfinal_kernel<<<1, 256, 0, stream>>>(sums, sumsq, gam[1], bet[1], scb);

    // block 3
    gemm_mfma<256, true><<<dim3(LL / 64, GG), 256, 0, stream>>>(a, amax, scb, Wf[2], hw);
    agg_kernel<<<GG * LL / 4, 256, 0, stream>>>(hw, bia[2], rowptr, edges, a);
    hipMemsetAsync(sums, 0, 2 * 256 * 4, stream);
    maxstats_kernel<<<BB * (LL / 16), 128, 0, stream>>>(a, amax, sums, sumsq);
    bnfinal_kernel<<<1, 256, 0, stream>>>(sums, sumsq, gam[2], bet[2], scb);

    // fused BN + ReLU + transpose to output layout
    transpose_norm_out<<<dim3(LL / 32, CC / 32, GG), dim3(32, 8), 0, stream>>>(a, amax, scb, out);
}

// Round 4
// 561.361 us; speedup vs baseline: 3.0425x; 1.0642x over previous
//
#include <hip/hip_runtime.h>
#include <hip/hip_bf16.h>
#include <cstddef>
#include <cstdint>

#define BB 4
#define NN 16
#define GG 64          // BB*NN
#define LL 2048
#define EE 32768
#define EF (EE + LL)   // edges + self loops
#define C0 64
#define CC 256
#define EPS 1e-5f

typedef __bf16 bf16x8 __attribute__((ext_vector_type(8)));
typedef __bf16 bf16x4 __attribute__((ext_vector_type(4)));
typedef __bf16 bf16x2 __attribute__((ext_vector_type(2)));
typedef float f32x4 __attribute__((ext_vector_type(4)));

struct __align__(8) Edge { int col; float val; };

// ---------------- edge preprocessing ----------------

__global__ void detect_kernel(const int* __restrict__ ei, int* __restrict__ flag) {
    int t = threadIdx.x;  // 64 threads, 1 wave
    int bad = 0;
    for (int i = t; i < 256; i += 64) bad |= (ei[2 * i + 1] != 0) ? 1 : 0;
    int any = __any(bad);
    if (t == 0) *flag = any ? 0 : 1;  // 1 => data is int64
}

// convert edges to int32 + init deg/cnt + zero BN stat accumulators
__global__ void prep_init_kernel(const void* __restrict__ ei, const int* __restrict__ flag,
                                 int* __restrict__ e32, float* __restrict__ deg,
                                 int* __restrict__ cnt, float* __restrict__ sums) {
    int i = blockIdx.x * 256 + threadIdx.x;
    if (i < 2 * EE) {
        int v;
        if (*flag)
            v = (int)((const long long*)ei)[i];
        else
            v = ((const int*)ei)[i];
        e32[i] = v;
    }
    if (i < LL) { deg[i] = 2.0f; cnt[i] = 1; }   // self-loop weight 2, one slot
    if (i < 512) sums[i] = 0.0f;                  // sums[256] + sumsq[256] adjacent
}

__global__ void deg_kernel(const int* __restrict__ e32, float* __restrict__ deg,
                           int* __restrict__ cnt) {
    int e = blockIdx.x * 256 + threadIdx.x;
    if (e >= EE) return;
    int d = e32[EE + e];
    atomicAdd(&deg[d], 1.0f);
    atomicAdd(&cnt[d], 1);
}

// prefix-scan of cnt -> rowptr/cursor, plus dinv = rsqrt(deg)
__global__ void scan_dinv_kernel(const int* __restrict__ cnt, const float* __restrict__ deg,
                                 int* __restrict__ rowptr, int* __restrict__ cursor,
                                 float* __restrict__ dinv) {
    __shared__ int part[256];
    int t = threadIdx.x;
    int base = t * 8;
    int loc[8];
    int s = 0;
#pragma unroll
    for (int j = 0; j < 8; ++j) {
        loc[j] = s; s += cnt[base + j];
        dinv[base + j] = rsqrtf(deg[base + j]);
    }
    part[t] = s;
    __syncthreads();
    if (t == 0) {
        int run = 0;
        for (int i = 0; i < 256; ++i) { int v = part[i]; part[i] = run; run += v; }
    }
    __syncthreads();
    int off = part[t];
#pragma unroll
    for (int j = 0; j < 8; ++j) {
        int rp = off + loc[j];
        rowptr[base + j] = rp;
        cursor[base + j] = rp;
    }
    if (t == 255) rowptr[LL] = off + s;
}

__global__ void fill_kernel(const int* __restrict__ e32, const float* __restrict__ dinv,
                            int* __restrict__ cursor, Edge* __restrict__ edges) {
    int idx = blockIdx.x * 256 + threadIdx.x;
    if (idx >= EF) return;
    int s, d; float w;
    if (idx < EE) {
        s = e32[idx]; d = e32[EE + idx];
        w = dinv[s] * dinv[d];
    } else {
        int i = idx - EE;
        s = i; d = i;
        w = 2.0f * dinv[i] * dinv[i];
    }
    int pos = atomicAdd(&cursor[d], 1);
    edges[pos].col = s;
    edges[pos].val = w;
}

// ---------------- W pre-pack: W[K][128] f32 -> fragment-ordered bf16 ----------------
// Wf[((ks*8 + n16)*64 + lane)*8 + j] = bf16( W[ks*32 + (lane>>4)*8 + j][n16*16 + (lane&15)] )

__global__ void prep_w(const float* __restrict__ W, __bf16* __restrict__ Wf, int K) {
    int t = blockIdx.x * 256 + threadIdx.x;
    int total = (K / 32) * 8 * 64;
    if (t >= total) return;
    int lane = t & 63;
    int rest = t >> 6;
    int n16 = rest & 7;
    int ks = rest >> 3;
    int col = n16 * 16 + (lane & 15);
    int k0 = ks * 32 + (lane >> 4) * 8;
    bf16x8 v;
#pragma unroll
    for (int j = 0; j < 8; ++j) v[j] = (__bf16)W[(size_t)(k0 + j) * 128 + col];
    *(bf16x8*)(Wf + (size_t)t * 8) = v;
}

// ---------------- x transpose: [g][c=64][l] -> [g][l][64] f32 ----------------

__global__ void transpose_x(const float* __restrict__ x, float* __restrict__ h) {
    __shared__ float t[32][33];
    int g = blockIdx.z, c0 = blockIdx.y * 32, l0 = blockIdx.x * 32;
    int tx = threadIdx.x, ty = threadIdx.y;  // 32 x 8
    const float* xp = x + ((size_t)g * C0 + c0) * LL + l0;
#pragma unroll
    for (int i = ty; i < 32; i += 8) t[i][tx] = xp[(size_t)i * LL + tx];  // t[c][l]
    __syncthreads();
    float* hp = h + ((size_t)g * LL + l0) * C0 + c0;
#pragma unroll
    for (int i = ty; i < 32; i += 8) hp[(size_t)i * C0 + tx] = t[tx][i];
}

// ---------------- MFMA GEMM: hw[g][l][128] = act(A)[g][l][0:K] @ W[K][128] ----------------
// BN=true: A = relu(bn(concat(a, amax_broadcast))) applied on the fly at staging.
// grid (LL/64, GG), 256 threads (4 waves). Wave w computes rows [w*16, w*16+16) x all 128 cols.

template <int K, bool BN>
__global__ __launch_bounds__(256) void gemm_mfma(const float* __restrict__ A0,
                                                 const float* __restrict__ amax,
                                                 const float* __restrict__ scb,
                                                 const __bf16* __restrict__ Wf,
                                                 __bf16* __restrict__ hw) {
    const int g = blockIdx.y;
    const int l0 = blockIdx.x * 64;
    const int tid = threadIdx.x;
    const int wid = tid >> 6;
    const int lane = tid & 63;
    __shared__ __align__(16) __bf16 As[64 * 64];

    f32x4 acc[8];
#pragma unroll
    for (int nf = 0; nf < 8; ++nf) acc[nf] = (f32x4){0.f, 0.f, 0.f, 0.f};

    for (int kt = 0; kt < K / 64; ++kt) {
        // ---- stage A tile [64 rows][64 k] -> bf16 LDS, XOR-swizzled ----
#pragma unroll
        for (int it = 0; it < 4; ++it) {
            int f4 = tid + it * 256;     // 0..1023
            int row = f4 >> 4;           // 0..63
            int kq = (f4 & 15) * 4;      // 0..60
            int gk = kt * 64 + kq;
            float4 v;
            if constexpr (BN) {
                if (gk < 128)
                    v = *(const float4*)(A0 + ((size_t)g * LL + l0 + row) * 128 + gk);
                else
                    v = *(const float4*)(amax + ((size_t)(g >> 4) * LL + l0 + row) * 128 + (gk - 128));
                float4 s = *(const float4*)(scb + gk);
                float4 b = *(const float4*)(scb + 256 + gk);
                v.x = fmaxf(fmaf(v.x, s.x, b.x), 0.f);
                v.y = fmaxf(fmaf(v.y, s.y, b.y), 0.f);
                v.z = fmaxf(fmaf(v.z, s.z, b.z), 0.f);
                v.w = fmaxf(fmaf(v.w, s.w, b.w), 0.f);
            } else {
                v = *(const float4*)(A0 + ((size_t)g * LL + l0 + row) * 64 + gk);
            }
            int sidx = row * 64 + (kq ^ ((row & 7) << 3));
            bf16x4 pv = {(__bf16)v.x, (__bf16)v.y, (__bf16)v.z, (__bf16)v.w};
            *(bf16x4*)(&As[sidx]) = pv;
        }
        __syncthreads();
        // ---- MFMA over the 2 k-steps of this tile ----
#pragma unroll
        for (int ks2 = 0; ks2 < 2; ++ks2) {
            const int row = wid * 16 + (lane & 15);
            const int kk = ks2 * 32 + (lane >> 4) * 8;
            bf16x8 af = *(const bf16x8*)(&As[row * 64 + (kk ^ ((row & 7) << 3))]);
            const int ksg = kt * 2 + ks2;
            const __bf16* wp = Wf + (size_t)ksg * 8 * 512 + lane * 8;
#pragma unroll
            for (int nf = 0; nf < 8; ++nf) {
                bf16x8 bfr = *(const bf16x8*)(wp + nf * 512);
                acc[nf] = __builtin_amdgcn_mfma_f32_16x16x32_bf16(af, bfr, acc[nf], 0, 0, 0);
            }
        }
        __syncthreads();
    }
    // ---- epilogue: D frag col=lane&15, row=(lane>>4)*4+j ----
    __bf16* op = hw + ((size_t)g * LL + l0) * 128;
#pragma unroll
    for (int nf = 0; nf < 8; ++nf) {
        int col = nf * 16 + (lane & 15);
#pragma unroll
        for (int j = 0; j < 4; ++j) {
            int row = wid * 16 + (lane >> 4) * 4 + j;
            op[(size_t)row * 128 + col] = (__bf16)acc[nf][j];
        }
    }
}

// ---------------- aggregation: a[g][l][f] = bias[f] + sum_e val*hw[g][col][f] ----------------
// One wave per node. 16-lane group `grp` handles edges d+grp; lane&15 owns a channel
// octet (bf16x8 = 16B gather => 4 edges per load instruction). 2-deep unroll => 8 edges
// in flight. Cross-group butterfly reduce at the end. grid GG*LL/4, block 256.

__global__ __launch_bounds__(256) void agg_kernel(const __bf16* __restrict__ hw,
                                                  const float* __restrict__ bias,
                                                  const int* __restrict__ rowptr,
                                                  const Edge* __restrict__ edges,
                                                  float* __restrict__ aout) {
    const int lane = threadIdx.x & 63;
    const int grp = lane >> 4;      // edge sub-group 0..3
    const int ch16 = lane & 15;     // channel octet
    int node = blockIdx.x * 4 + (threadIdx.x >> 6);  // g*LL + l
    node = __builtin_amdgcn_readfirstlane(node);
    const int g = node >> 11, l = node & (LL - 1);
    const __bf16* __restrict__ base = hw + (size_t)g * LL * 128 + ch16 * 8;
    const int j0 = rowptr[l];
    const int deg = rowptr[l + 1] - j0;

    float acc[8];
#pragma unroll
    for (int j = 0; j < 8; ++j) acc[j] = 0.0f;

    for (int d0 = 0; d0 < deg; d0 += 64) {
        const int cnt = min(64, deg - d0);
        Edge e;
        e.col = 0; e.val = 0.0f;   // masked lanes contribute 0 via val=0
        if (lane < cnt) e = edges[j0 + d0 + lane];
        int d = 0;
        for (; d + 8 <= cnt; d += 8) {
            int i1 = d + grp, i2 = d + 4 + grp;
            int c1 = __shfl(e.col, i1); float w1 = __shfl(e.val, i1);
            int c2 = __shfl(e.col, i2); float w2 = __shfl(e.val, i2);
            bf16x8 v1 = *(const bf16x8*)(base + (size_t)c1 * 128);
            bf16x8 v2 = *(const bf16x8*)(base + (size_t)c2 * 128);
#pragma unroll
            for (int j = 0; j < 8; ++j) acc[j] = fmaf(w1, (float)v1[j], acc[j]);
#pragma unroll
            for (int j = 0; j < 8; ++j) acc[j] = fmaf(w2, (float)v2[j], acc[j]);
        }
        for (; d < cnt; d += 4) {
            int i1 = d + grp;
            int c1 = __shfl(e.col, i1); float w1 = __shfl(e.val, i1);
            bf16x8 v1 = *(const bf16x8*)(base + (size_t)c1 * 128);
#pragma unroll
            for (int j = 0; j < 8; ++j) acc[j] = fmaf(w1, (float)v1[j], acc[j]);
        }
    }
    // butterfly over the 4 edge groups
#pragma unroll
    for (int j = 0; j < 8; ++j) {
        acc[j] += __shfl_xor(acc[j], 16);
        acc[j] += __shfl_xor(acc[j], 32);
    }
    if (grp == 0) {
        float4 b0 = *(const float4*)(bias + ch16 * 8);
        float4 b1 = *(const float4*)(bias + ch16 * 8 + 4);
        float4 s0 = make_float4(acc[0] + b0.x, acc[1] + b0.y, acc[2] + b0.z, acc[3] + b0.w);
        float4 s1 = make_float4(acc[4] + b1.x, acc[5] + b1.y, acc[6] + b1.z, acc[7] + b1.w);
        float* op = aout + (size_t)node * 128 + ch16 * 8;
        *(float4*)op = s0;
        *(float4*)(op + 4) = s1;
    }
}

// ---------------- max over n + BN stats ----------------
// a: [g][l][128] f32. grid BB*(LL/16), block 128.

__global__ void maxstats_kernel(const float* __restrict__ a, float* __restrict__ amax,
                                float* __restrict__ sums, float* __restrict__ sumsq) {
    int bb = blockIdx.x >> 7;      // LL/16 = 128 tiles per b
    int lt = blockIdx.x & 127;
    int l0 = lt * 16;
    int f = threadIdx.x;
    float s = 0.f, ss = 0.f, sa = 0.f, ssa = 0.f;
    for (int li = 0; li < 16; ++li) {
        int l = l0 + li;
        float m = -3.402823466e38f;
#pragma unroll
        for (int n = 0; n < NN; ++n) {
            float v = a[(((size_t)(bb * NN + n) * LL + l) * 128) + f];
            m = fmaxf(m, v);
            s += v;
            ss = fmaf(v, v, ss);
        }
        amax[((size_t)bb * LL + l) * 128 + f] = m;
        sa += m;
        ssa = fmaf(m, m, ssa);
    }
    atomicAdd(&sums[f], s);
    atomicAdd(&sumsq[f], ss);
    atomicAdd(&sums[128 + f], sa);
    atomicAdd(&sumsq[128 + f], ssa);
}

// reads stats -> scale/bias, then self-clears accumulators for the next block
__global__ void bnfinal_kernel(float* __restrict__ sums, float* __restrict__ sumsq,
                               const float* __restrict__ gamma, const float* __restrict__ beta,
                               float* __restrict__ scb) {
    int f = threadIdx.x;  // 256
    float cntv = (f < 128) ? (float)(BB * NN * LL) : (float)(BB * LL);
    float mean = sums[f] / cntv;
    float var = sumsq[f] / cntv - mean * mean;
    float s = gamma[f] * rsqrtf(var + EPS);
    scb[f] = s;
    scb[256 + f] = beta[f] - mean * s;
    sums[f] = 0.0f;
    sumsq[f] = 0.0f;
}

// ---------------- final: out[g][f][l] = relu(bn(concat(a, amax))) transposed ----------------
// 64x64 tiles for 256B/wave loads AND stores. grid (LL/64, CC/64, GG), block (64,8).

__global__ void transpose_norm_out(const float* __restrict__ a, const float* __restrict__ amax,
                                   const float* __restrict__ scb, float* __restrict__ out) {
    __shared__ float t[64][65];
    int g = blockIdx.z, f0 = blockIdx.y * 64, l0 = blockIdx.x * 64;
    int tx = threadIdx.x, ty = threadIdx.y;  // 64 x 8
    int f = f0 + tx;
    float s = scb[f], b = scb[256 + f];
#pragma unroll
    for (int i = ty; i < 64; i += 8) {
        int l = l0 + i;
        float v;
        if (f0 < 128)
            v = a[((size_t)g * LL + l) * 128 + f];
        else
            v = amax[((size_t)(g >> 4) * LL + l) * 128 + (f - 128)];
        t[i][tx] = fmaxf(fmaf(v, s, b), 0.f);
    }
    __syncthreads();
    float* op = out + ((size_t)g * CC + f0) * LL + l0;
#pragma unroll
    for (int i = ty; i < 64; i += 8) op[(size_t)i * LL + tx] = t[tx][i];
}

// ---------------- launch ----------------

extern "C" void kernel_launch(void* const* d_in, const int* in_sizes, int n_in,
                              void* d_out, int out_size, void* d_ws, size_t ws_size,
                              hipStream_t stream) {
    const float* x = (const float*)d_in[0];
    const void* ei = d_in[1];
    const float* W[3] = {(const float*)d_in[2], (const float*)d_in[4], (const float*)d_in[6]};
    const float* bia[3] = {(const float*)d_in[3], (const float*)d_in[5], (const float*)d_in[7]};
    const float* gam[3] = {(const float*)d_in[8], (const float*)d_in[10], (const float*)d_in[12]};
    const float* bet[3] = {(const float*)d_in[9], (const float*)d_in[11], (const float*)d_in[13]};
    float* out = (float*)d_out;

    char* w = (char*)d_ws;
    float* h0   = (float*)w;  w += (size_t)GG * LL * C0 * 4;    // 33.5MB
    float* a    = (float*)w;  w += (size_t)GG * LL * 128 * 4;   // 67MB
    __bf16* hw  = (__bf16*)w; w += (size_t)GG * LL * 128 * 2;   // 33.5MB
    float* amax = (float*)w;  w += (size_t)BB * LL * 128 * 4;   // 4MB
    __bf16* Wf[3];
    Wf[0] = (__bf16*)w; w += 65536 * 2;
    Wf[1] = (__bf16*)w; w += 65536 * 2;
    Wf[2] = (__bf16*)w; w += 65536 * 2;
    int*   e32   = (int*)w;    w += (size_t)2 * EE * 4;
    float* deg   = (float*)w;  w += LL * 4;
    int*   cnt   = (int*)w;    w += LL * 4;
    int*   rowptr= (int*)w;    w += (LL + 4) * 4;
    int*   cursor= (int*)w;    w += LL * 4;
    Edge*  edges = (Edge*)w;   w += (size_t)EF * 8;
    float* dinv  = (float*)w;  w += LL * 4;
    float* sums  = (float*)w;  w += 256 * 4;   // sums[256] then sumsq[256] contiguous
    float* sumsq = (float*)w;  w += 256 * 4;
    float* scb   = (float*)w;  w += 512 * 4;
    int*   flag  = (int*)w;    w += 256;

    // edge preprocessing (convert+init merged; scan+dinv merged; bnfinal self-clears stats)
    detect_kernel<<<1, 64, 0, stream>>>((const int*)ei, flag);
    prep_init_kernel<<<(2 * EE + 255) / 256, 256, 0, stream>>>(ei, flag, e32, deg, cnt, sums);
    deg_kernel<<<(EE + 255) / 256, 256, 0, stream>>>(e32, deg, cnt);
    scan_dinv_kernel<<<1, 256, 0, stream>>>(cnt, deg, rowptr, cursor, dinv);
    fill_kernel<<<(EF + 255) / 256, 256, 0, stream>>>(e32, dinv, cursor, edges);

    // weight pre-pack
    prep_w<<<(1024 + 255) / 256, 256, 0, stream>>>(W[0], Wf[0], 64);
    prep_w<<<(4096 + 255) / 256, 256, 0, stream>>>(W[1], Wf[1], 256);
    prep_w<<<(4096 + 255) / 256, 256, 0, stream>>>(W[2], Wf[2], 256);

    // input transpose
    transpose_x<<<dim3(LL / 32, C0 / 32, GG), dim3(32, 8), 0, stream>>>(x, h0);

    // block 1
    gemm_mfma<64, false><<<dim3(LL / 64, GG), 256, 0, stream>>>(h0, amax, scb, Wf[0], hw);
    agg_kernel<<<GG * LL / 4, 256, 0, stream>>>(hw, bia[0], rowptr, edges, a);
    maxstats_kernel<<<BB * (LL / 16), 128, 0, stream>>>(a, amax, sums, sumsq);
    bnfinal_kernel<<<1, 256, 0, stream>>>(sums, sumsq, gam[0], bet[0], scb);

    // block 2
    gemm_mfma<256, true><<<dim3(LL / 64, GG), 256, 0, stream>>>(a, amax, scb, Wf[1], hw);
    agg_kernel<<<GG * LL / 4, 256, 0, stream>>>(hw, bia[1], rowptr, edges, a);
    maxstats_kernel<<<BB * (LL / 16), 128, 0, stream>>>(a, amax, sums, sumsq);
    bnfinal_kernel<<<1, 256, 0, stream>>>(sums, sumsq, gam[1], bet[1], scb);

    // block 3
    gemm_mfma<256, true><<<dim3(LL / 64, GG), 256, 0, stream>>>(a, amax, scb, Wf[2], hw);
    agg_kernel<<<GG * LL / 4, 256, 0, stream>>>(hw, bia[2], rowptr, edges, a);
    maxstats_kernel<<<BB * (LL / 16), 128, 0, stream>>>(a, amax, sums, sumsq);
    bnfinal_kernel<<<1, 256, 0, stream>>>(sums, sumsq, gam[2], bet[2], scb);

    // fused BN + ReLU + transpose to output layout
    transpose_norm_out<<<dim3(LL / 64, CC / 64, GG), dim3(64, 8), 0, stream>>>(a, amax, scb, out);
}

// Round 5
// 531.591 us; speedup vs baseline: 3.2129x; 1.0560x over previous
//
#include <hip/hip_runtime.h>
#include <hip/hip_bf16.h>
#include <cstddef>
#include <cstdint>

#define BB 4
#define NN 16
#define GG 64          // BB*NN
#define LL 2048
#define EE 32768
#define EF (EE + LL)   // edges + self loops
#define C0 64
#define CC 256
#define EPS 1e-5f

typedef __bf16 bf16x8 __attribute__((ext_vector_type(8)));
typedef __bf16 bf16x4 __attribute__((ext_vector_type(4)));
typedef __bf16 bf16x2 __attribute__((ext_vector_type(2)));
typedef float f32x4 __attribute__((ext_vector_type(4)));

struct __align__(8) Edge { int col; float val; };

// ---------------- edge preprocessing ----------------

__global__ void detect_kernel(const int* __restrict__ ei, int* __restrict__ flag) {
    int t = threadIdx.x;  // 64 threads, 1 wave
    int bad = 0;
    for (int i = t; i < 256; i += 64) bad |= (ei[2 * i + 1] != 0) ? 1 : 0;
    int any = __any(bad);
    if (t == 0) *flag = any ? 0 : 1;  // 1 => data is int64
}

// convert edges to int32 + init deg/cnt + zero BN stat accumulators
__global__ void prep_init_kernel(const void* __restrict__ ei, const int* __restrict__ flag,
                                 int* __restrict__ e32, float* __restrict__ deg,
                                 int* __restrict__ cnt, float* __restrict__ sums) {
    int i = blockIdx.x * 256 + threadIdx.x;
    if (i < 2 * EE) {
        int v;
        if (*flag)
            v = (int)((const long long*)ei)[i];
        else
            v = ((const int*)ei)[i];
        e32[i] = v;
    }
    if (i < LL) { deg[i] = 2.0f; cnt[i] = 1; }   // self-loop weight 2, one slot
    if (i < 512) sums[i] = 0.0f;                  // sums[256] + sumsq[256] adjacent
}

__global__ void deg_kernel(const int* __restrict__ e32, float* __restrict__ deg,
                           int* __restrict__ cnt) {
    int e = blockIdx.x * 256 + threadIdx.x;
    if (e >= EE) return;
    int d = e32[EE + e];
    atomicAdd(&deg[d], 1.0f);
    atomicAdd(&cnt[d], 1);
}

// prefix-scan of cnt -> rowptr/cursor, plus dinv = rsqrt(deg)
__global__ void scan_dinv_kernel(const int* __restrict__ cnt, const float* __restrict__ deg,
                                 int* __restrict__ rowptr, int* __restrict__ cursor,
                                 float* __restrict__ dinv) {
    __shared__ int part[256];
    int t = threadIdx.x;
    int base = t * 8;
    int loc[8];
    int s = 0;
#pragma unroll
    for (int j = 0; j < 8; ++j) {
        loc[j] = s; s += cnt[base + j];
        dinv[base + j] = rsqrtf(deg[base + j]);
    }
    part[t] = s;
    __syncthreads();
    if (t == 0) {
        int run = 0;
        for (int i = 0; i < 256; ++i) { int v = part[i]; part[i] = run; run += v; }
    }
    __syncthreads();
    int off = part[t];
#pragma unroll
    for (int j = 0; j < 8; ++j) {
        int rp = off + loc[j];
        rowptr[base + j] = rp;
        cursor[base + j] = rp;
    }
    if (t == 255) rowptr[LL] = off + s;
}

__global__ void fill_kernel(const int* __restrict__ e32, const float* __restrict__ dinv,
                            int* __restrict__ cursor, Edge* __restrict__ edges) {
    int idx = blockIdx.x * 256 + threadIdx.x;
    if (idx >= EF) return;
    int s, d; float w;
    if (idx < EE) {
        s = e32[idx]; d = e32[EE + idx];
        w = dinv[s] * dinv[d];
    } else {
        int i = idx - EE;
        s = i; d = i;
        w = 2.0f * dinv[i] * dinv[i];
    }
    int pos = atomicAdd(&cursor[d], 1);
    edges[pos].col = s;
    edges[pos].val = w;
}

// ---------------- W pre-pack: all 3 weights in one launch ----------------
// Wf[((ks*8 + n16)*64 + lane)*8 + j] = bf16( W[ks*32 + (lane>>4)*8 + j][n16*16 + (lane&15)] )
// grid covers 1024 + 4096 + 4096 frag-threads.

__global__ void prep_w_all(const float* __restrict__ W0, const float* __restrict__ W1,
                           const float* __restrict__ W2, __bf16* __restrict__ Wf0,
                           __bf16* __restrict__ Wf1, __bf16* __restrict__ Wf2) {
    int t = blockIdx.x * 256 + threadIdx.x;
    const float* W; __bf16* Wf;
    if (t < 1024)      { W = W0; Wf = Wf0; }
    else if (t < 5120) { W = W1; Wf = Wf1; t -= 1024; }
    else if (t < 9216) { W = W2; Wf = Wf2; t -= 5120; }
    else return;
    int lane = t & 63;
    int rest = t >> 6;
    int n16 = rest & 7;
    int ks = rest >> 3;
    int col = n16 * 16 + (lane & 15);
    int k0 = ks * 32 + (lane >> 4) * 8;
    bf16x8 v;
#pragma unroll
    for (int j = 0; j < 8; ++j) v[j] = (__bf16)W[(size_t)(k0 + j) * 128 + col];
    *(bf16x8*)(Wf + (size_t)t * 8) = v;
}

// ---------------- x transpose: [g][c=64][l] -> [g][l][64] f32 ----------------

__global__ void transpose_x(const float* __restrict__ x, float* __restrict__ h) {
    __shared__ float t[32][33];
    int g = blockIdx.z, c0 = blockIdx.y * 32, l0 = blockIdx.x * 32;
    int tx = threadIdx.x, ty = threadIdx.y;  // 32 x 8
    const float* xp = x + ((size_t)g * C0 + c0) * LL + l0;
#pragma unroll
    for (int i = ty; i < 32; i += 8) t[i][tx] = xp[(size_t)i * LL + tx];  // t[c][l]
    __syncthreads();
    float* hp = h + ((size_t)g * LL + l0) * C0 + c0;
#pragma unroll
    for (int i = ty; i < 32; i += 8) hp[(size_t)i * C0 + tx] = t[tx][i];
}

// ---------------- MFMA GEMM: hw[g][l][128] = act(A)[g][l][0:K] @ W[K][128] ----------------
// BN=true: A = relu(bn(concat(a, amax_broadcast))) applied on the fly at staging.
// grid (LL/64, GG), 256 threads (4 waves). Wave w computes rows [w*16, w*16+16) x all 128 cols.

template <int K, bool BN>
__global__ __launch_bounds__(256) void gemm_mfma(const float* __restrict__ A0,
                                                 const float* __restrict__ amax,
                                                 const float* __restrict__ scb,
                                                 const __bf16* __restrict__ Wf,
                                                 __bf16* __restrict__ hw) {
    const int g = blockIdx.y;
    const int l0 = blockIdx.x * 64;
    const int tid = threadIdx.x;
    const int wid = tid >> 6;
    const int lane = tid & 63;
    __shared__ __align__(16) __bf16 As[64 * 64];

    f32x4 acc[8];
#pragma unroll
    for (int nf = 0; nf < 8; ++nf) acc[nf] = (f32x4){0.f, 0.f, 0.f, 0.f};

    for (int kt = 0; kt < K / 64; ++kt) {
        // ---- stage A tile [64 rows][64 k] -> bf16 LDS, XOR-swizzled ----
#pragma unroll
        for (int it = 0; it < 4; ++it) {
            int f4 = tid + it * 256;     // 0..1023
            int row = f4 >> 4;           // 0..63
            int kq = (f4 & 15) * 4;      // 0..60
            int gk = kt * 64 + kq;
            float4 v;
            if constexpr (BN) {
                if (gk < 128)
                    v = *(const float4*)(A0 + ((size_t)g * LL + l0 + row) * 128 + gk);
                else
                    v = *(const float4*)(amax + ((size_t)(g >> 4) * LL + l0 + row) * 128 + (gk - 128));
                float4 s = *(const float4*)(scb + gk);
                float4 b = *(const float4*)(scb + 256 + gk);
                v.x = fmaxf(fmaf(v.x, s.x, b.x), 0.f);
                v.y = fmaxf(fmaf(v.y, s.y, b.y), 0.f);
                v.z = fmaxf(fmaf(v.z, s.z, b.z), 0.f);
                v.w = fmaxf(fmaf(v.w, s.w, b.w), 0.f);
            } else {
                v = *(const float4*)(A0 + ((size_t)g * LL + l0 + row) * 64 + gk);
            }
            int sidx = row * 64 + (kq ^ ((row & 7) << 3));
            bf16x4 pv = {(__bf16)v.x, (__bf16)v.y, (__bf16)v.z, (__bf16)v.w};
            *(bf16x4*)(&As[sidx]) = pv;
        }
        __syncthreads();
        // ---- MFMA over the 2 k-steps of this tile ----
#pragma unroll
        for (int ks2 = 0; ks2 < 2; ++ks2) {
            const int row = wid * 16 + (lane & 15);
            const int kk = ks2 * 32 + (lane >> 4) * 8;
            bf16x8 af = *(const bf16x8*)(&As[row * 64 + (kk ^ ((row & 7) << 3))]);
            const int ksg = kt * 2 + ks2;
            const __bf16* wp = Wf + (size_t)ksg * 8 * 512 + lane * 8;
#pragma unroll
            for (int nf = 0; nf < 8; ++nf) {
                bf16x8 bfr = *(const bf16x8*)(wp + nf * 512);
                acc[nf] = __builtin_amdgcn_mfma_f32_16x16x32_bf16(af, bfr, acc[nf], 0, 0, 0);
            }
        }
        __syncthreads();
    }
    // ---- epilogue: D frag col=lane&15, row=(lane>>4)*4+j ----
    __bf16* op = hw + ((size_t)g * LL + l0) * 128;
#pragma unroll
    for (int nf = 0; nf < 8; ++nf) {
        int col = nf * 16 + (lane & 15);
#pragma unroll
        for (int j = 0; j < 4; ++j) {
            int row = wid * 16 + (lane >> 4) * 4 + j;
            op[(size_t)row * 128 + col] = (__bf16)acc[nf][j];
        }
    }
}

// ---------------- aggregation: a[g][l][f] = bias[f] + sum_e val*hw[g][col][f] ----------------
// One wave per node. 16-lane group `grp` handles edges d+grp; lane&15 owns a channel
// octet (bf16x8 = 16B gather => 4 edges per load instruction). 2-deep unroll => 8 edges
// in flight. Cross-group butterfly reduce at the end.
// XCD-pinned block swizzle: all 512 blocks of a graph land on one XCD so its 512KB hw
// slice stays hot in that XCD's private L2 (kills the ~4-7x cross-XCD HBM over-fetch).
// grid GG*LL/4 = 32768 blocks, block 256.

__global__ __launch_bounds__(256) void agg_kernel(const __bf16* __restrict__ hw,
                                                  const float* __restrict__ bias,
                                                  const int* __restrict__ rowptr,
                                                  const Edge* __restrict__ edges,
                                                  float* __restrict__ aout) {
    const int lane = threadIdx.x & 63;
    const int grp = lane >> 4;      // edge sub-group 0..3
    const int ch16 = lane & 15;     // channel octet
    // ---- XCD-pinning swizzle (HW round-robins linear block id across 8 XCDs) ----
    const int bid = blockIdx.x;
    const int xcd = bid & 7;
    const int slot = bid >> 3;                 // 0..4095
    const int gswz = ((slot >> 9) << 3) + xcd; // graph 0..63, pinned to xcd
    const int within = slot & 511;             // 512 blocks per graph
    int node = (gswz << 11) + within * 4 + (threadIdx.x >> 6);  // g*LL + l
    node = __builtin_amdgcn_readfirstlane(node);
    const int g = node >> 11, l = node & (LL - 1);
    const __bf16* __restrict__ base = hw + (size_t)g * LL * 128 + ch16 * 8;
    const int j0 = rowptr[l];
    const int deg = rowptr[l + 1] - j0;

    float acc[8];
#pragma unroll
    for (int j = 0; j < 8; ++j) acc[j] = 0.0f;

    for (int d0 = 0; d0 < deg; d0 += 64) {
        const int cnt = min(64, deg - d0);
        Edge e;
        e.col = 0; e.val = 0.0f;   // masked lanes contribute 0 via val=0
        if (lane < cnt) e = edges[j0 + d0 + lane];
        int d = 0;
        for (; d + 8 <= cnt; d += 8) {
            int i1 = d + grp, i2 = d + 4 + grp;
            int c1 = __shfl(e.col, i1); float w1 = __shfl(e.val, i1);
            int c2 = __shfl(e.col, i2); float w2 = __shfl(e.val, i2);
            bf16x8 v1 = *(const bf16x8*)(base + (size_t)c1 * 128);
            bf16x8 v2 = *(const bf16x8*)(base + (size_t)c2 * 128);
#pragma unroll
            for (int j = 0; j < 8; ++j) acc[j] = fmaf(w1, (float)v1[j], acc[j]);
#pragma unroll
            for (int j = 0; j < 8; ++j) acc[j] = fmaf(w2, (float)v2[j], acc[j]);
        }
        for (; d < cnt; d += 4) {
            int i1 = d + grp;
            int c1 = __shfl(e.col, i1); float w1 = __shfl(e.val, i1);
            bf16x8 v1 = *(const bf16x8*)(base + (size_t)c1 * 128);
#pragma unroll
            for (int j = 0; j < 8; ++j) acc[j] = fmaf(w1, (float)v1[j], acc[j]);
        }
    }
    // butterfly over the 4 edge groups
#pragma unroll
    for (int j = 0; j < 8; ++j) {
        acc[j] += __shfl_xor(acc[j], 16);
        acc[j] += __shfl_xor(acc[j], 32);
    }
    if (grp == 0) {
        float4 b0 = *(const float4*)(bias + ch16 * 8);
        float4 b1 = *(const float4*)(bias + ch16 * 8 + 4);
        float4 s0 = make_float4(acc[0] + b0.x, acc[1] + b0.y, acc[2] + b0.z, acc[3] + b0.w);
        float4 s1 = make_float4(acc[4] + b1.x, acc[5] + b1.y, acc[6] + b1.z, acc[7] + b1.w);
        float* op = aout + (size_t)node * 128 + ch16 * 8;
        *(float4*)op = s0;
        *(float4*)(op + 4) = s1;
    }
}

// ---------------- max over n + BN stats ----------------
// a: [g][l][128] f32. grid BB*(LL/16), block 128.

__global__ void maxstats_kernel(const float* __restrict__ a, float* __restrict__ amax,
                                float* __restrict__ sums, float* __restrict__ sumsq) {
    int bb = blockIdx.x >> 7;      // LL/16 = 128 tiles per b
    int lt = blockIdx.x & 127;
    int l0 = lt * 16;
    int f = threadIdx.x;
    float s = 0.f, ss = 0.f, sa = 0.f, ssa = 0.f;
    for (int li = 0; li < 16; ++li) {
        int l = l0 + li;
        float m = -3.402823466e38f;
#pragma unroll
        for (int n = 0; n < NN; ++n) {
            float v = a[(((size_t)(bb * NN + n) * LL + l) * 128) + f];
            m = fmaxf(m, v);
            s += v;
            ss = fmaf(v, v, ss);
        }
        amax[((size_t)bb * LL + l) * 128 + f] = m;
        sa += m;
        ssa = fmaf(m, m, ssa);
    }
    atomicAdd(&sums[f], s);
    atomicAdd(&sumsq[f], ss);
    atomicAdd(&sums[128 + f], sa);
    atomicAdd(&sumsq[128 + f], ssa);
}

// reads stats -> scale/bias, then self-clears accumulators for the next block
__global__ void bnfinal_kernel(float* __restrict__ sums, float* __restrict__ sumsq,
                               const float* __restrict__ gamma, const float* __restrict__ beta,
                               float* __restrict__ scb) {
    int f = threadIdx.x;  // 256
    float cntv = (f < 128) ? (float)(BB * NN * LL) : (float)(BB * LL);
    float mean = sums[f] / cntv;
    float var = sumsq[f] / cntv - mean * mean;
    float s = gamma[f] * rsqrtf(var + EPS);
    scb[f] = s;
    scb[256 + f] = beta[f] - mean * s;
    sums[f] = 0.0f;
    sumsq[f] = 0.0f;
}

// ---------------- final: out[g][f][l] = relu(bn(concat(a, amax))) transposed ----------------
// 64x64 tiles for 256B/wave loads AND stores. grid (LL/64, CC/64, GG), block (64,8).

__global__ void transpose_norm_out(const float* __restrict__ a, const float* __restrict__ amax,
                                   const float* __restrict__ scb, float* __restrict__ out) {
    __shared__ float t[64][65];
    int g = blockIdx.z, f0 = blockIdx.y * 64, l0 = blockIdx.x * 64;
    int tx = threadIdx.x, ty = threadIdx.y;  // 64 x 8
    int f = f0 + tx;
    float s = scb[f], b = scb[256 + f];
#pragma unroll
    for (int i = ty; i < 64; i += 8) {
        int l = l0 + i;
        float v;
        if (f0 < 128)
            v = a[((size_t)g * LL + l) * 128 + f];
        else
            v = amax[((size_t)(g >> 4) * LL + l) * 128 + (f - 128)];
        t[i][tx] = fmaxf(fmaf(v, s, b), 0.f);
    }
    __syncthreads();
    float* op = out + ((size_t)g * CC + f0) * LL + l0;
#pragma unroll
    for (int i = ty; i < 64; i += 8) op[(size_t)i * LL + tx] = t[tx][i];
}

// ---------------- launch ----------------

extern "C" void kernel_launch(void* const* d_in, const int* in_sizes, int n_in,
                              void* d_out, int out_size, void* d_ws, size_t ws_size,
                              hipStream_t stream) {
    const float* x = (const float*)d_in[0];
    const void* ei = d_in[1];
    const float* W[3] = {(const float*)d_in[2], (const float*)d_in[4], (const float*)d_in[6]};
    const float* bia[3] = {(const float*)d_in[3], (const float*)d_in[5], (const float*)d_in[7]};
    const float* gam[3] = {(const float*)d_in[8], (const float*)d_in[10], (const float*)d_in[12]};
    const float* bet[3] = {(const float*)d_in[9], (const float*)d_in[11], (const float*)d_in[13]};
    float* out = (float*)d_out;

    char* w = (char*)d_ws;
    float* h0   = (float*)w;  w += (size_t)GG * LL * C0 * 4;    // 33.5MB
    float* a    = (float*)w;  w += (size_t)GG * LL * 128 * 4;   // 67MB
    __bf16* hw  = (__bf16*)w; w += (size_t)GG * LL * 128 * 2;   // 33.5MB
    float* amax = (float*)w;  w += (size_t)BB * LL * 128 * 4;   // 4MB
    __bf16* Wf[3];
    Wf[0] = (__bf16*)w; w += 65536 * 2;
    Wf[1] = (__bf16*)w; w += 65536 * 2;
    Wf[2] = (__bf16*)w; w += 65536 * 2;
    int*   e32   = (int*)w;    w += (size_t)2 * EE * 4;
    float* deg   = (float*)w;  w += LL * 4;
    int*   cnt   = (int*)w;    w += LL * 4;
    int*   rowptr= (int*)w;    w += (LL + 4) * 4;
    int*   cursor= (int*)w;    w += LL * 4;
    Edge*  edges = (Edge*)w;   w += (size_t)EF * 8;
    float* dinv  = (float*)w;  w += LL * 4;
    float* sums  = (float*)w;  w += 256 * 4;   // sums[256] then sumsq[256] contiguous
    float* sumsq = (float*)w;  w += 256 * 4;
    float* scb   = (float*)w;  w += 512 * 4;
    int*   flag  = (int*)w;    w += 256;

    // edge preprocessing (convert+init merged; scan+dinv merged; bnfinal self-clears stats)
    detect_kernel<<<1, 64, 0, stream>>>((const int*)ei, flag);
    prep_init_kernel<<<(2 * EE + 255) / 256, 256, 0, stream>>>(ei, flag, e32, deg, cnt, sums);
    deg_kernel<<<(EE + 255) / 256, 256, 0, stream>>>(e32, deg, cnt);
    scan_dinv_kernel<<<1, 256, 0, stream>>>(cnt, deg, rowptr, cursor, dinv);
    fill_kernel<<<(EF + 255) / 256, 256, 0, stream>>>(e32, dinv, cursor, edges);

    // weight pre-pack (all 3 in one launch)
    prep_w_all<<<36, 256, 0, stream>>>(W[0], W[1], W[2], Wf[0], Wf[1], Wf[2]);

    // input transpose
    transpose_x<<<dim3(LL / 32, C0 / 32, GG), dim3(32, 8), 0, stream>>>(x, h0);

    // block 1
    gemm_mfma<64, false><<<dim3(LL / 64, GG), 256, 0, stream>>>(h0, amax, scb, Wf[0], hw);
    agg_kernel<<<GG * LL / 4, 256, 0, stream>>>(hw, bia[0], rowptr, edges, a);
    maxstats_kernel<<<BB * (LL / 16), 128, 0, stream>>>(a, amax, sums, sumsq);
    bnfinal_kernel<<<1, 256, 0, stream>>>(sums, sumsq, gam[0], bet[0], scb);

    // block 2
    gemm_mfma<256, true><<<dim3(LL / 64, GG), 256, 0, stream>>>(a, amax, scb, Wf[1], hw);
    agg_kernel<<<GG * LL / 4, 256, 0, stream>>>(hw, bia[1], rowptr, edges, a);
    maxstats_kernel<<<BB * (LL / 16), 128, 0, stream>>>(a, amax, sums, sumsq);
    bnfinal_kernel<<<1, 256, 0, stream>>>(sums, sumsq, gam[1], bet[1], scb);

    // block 3
    gemm_mfma<256, true><<<dim3(LL / 64, GG), 256, 0, stream>>>(a, amax, scb, Wf[2], hw);
    agg_kernel<<<GG * LL / 4, 256, 0, stream>>>(hw, bia[2], rowptr, edges, a);
    maxstats_kernel<<<BB * (LL / 16), 128, 0, stream>>>(a, amax, sums, sumsq);
    bnfinal_kernel<<<1, 256, 0, stream>>>(sums, sumsq, gam[2], bet[2], scb);

    // fused BN + ReLU + transpose to output layout
    transpose_norm_out<<<dim3(LL / 64, CC / 64, GG), dim3(64, 8), 0, stream>>>(a, amax, scb, out);
}